// Round 13
// baseline (125.372 us; speedup 1.0000x reference)
//
#include <hip/hip_runtime.h>
#include <math.h>

#define Vv 256
#define Ee 64
#define Hh 128
#define Nn 16384
#define Ll 24
#define G4 512      // 4*H
#define WB 16       // words per task (single M-tile; 2 blocks/CU)
#define NTHR 512    // 8 waves
#define NGRP (Nn / WB)      // 1024 groups
#define NTASK (NGRP * 2)    // 2048 tasks (group x dir) = grid

typedef _Float16 half8 __attribute__((ext_vector_type(8)));
typedef float f32x4 __attribute__((ext_vector_type(4)));

#define KS1 (-1.4426950408889634f)   // -log2(e): i,f,o rows -> 2^s = exp(-y)

// ---- fused prep + sort (blocks 0..127: prep @1024thr; block 128: counting sort @16 waves)
// XGq[d][c][u][bank] (f32, float4 per (c,u)): (emb[c]@Wih_d[j] + bih[j]+bhh[j]) * scale(bank),
//   j = bank*128+u. scale = KS1 for i,f,o (exp2-ready); g bank (2) RAW for Pade tanh.
//   r8 lesson: keep float4-per-(c,u); scalar gathers on bank-major blew HBM 5.6MB->908MB.
// BP[d][kt][bank][g2][u][e] (f16): Whh_d[j][k]*scale(bank), k=kt*32+g2*8+e (B-frag order).
__global__ __launch_bounds__(1024) void prep_sort_kernel(
    const float* __restrict__ emb,
    const float* __restrict__ Wih_f, const float* __restrict__ Whh_f,
    const float* __restrict__ bih_f, const float* __restrict__ bhh_f,
    const float* __restrict__ Wih_b, const float* __restrict__ Whh_b,
    const float* __restrict__ bih_b, const float* __restrict__ bhh_b,
    const int* __restrict__ lens,
    _Float16* __restrict__ BP, float* __restrict__ XGq,
    int* __restrict__ order) {
  const int tid = threadIdx.x;
  if (blockIdx.x == 128) {
    // ---- sort: 16 waves, wave-private histograms/cursors (16 iters/pass; ~4x less
    // same-address LDS-atomic serialization than r12's 4-copy version on 256 thr).
    __shared__ int cnt16[16][32];
    __shared__ int cur16[16][32];
    __shared__ int btot[32];
    const int w = tid >> 6;
    if (tid < 512) ((int*)cnt16)[tid] = 0;
    __syncthreads();
    for (int i = tid; i < Nn; i += 1024) atomicAdd(&cnt16[w][lens[i]], 1);
    __syncthreads();
    if (tid < 32) {  // per-bucket totals across the 16 wave-copies
      int s = 0;
#pragma unroll
      for (int ww = 0; ww < 16; ww++) s += cnt16[ww][tid];
      btot[tid] = s;
    }
    __syncthreads();
    if (tid == 0) {  // exclusive scan over 25 buckets
      int s = 0;
      for (int b = 0; b <= Ll; b++) { int tv = btot[b]; btot[b] = s; s += tv; }
    }
    __syncthreads();
    if (tid < 32) {  // per-(bucket, wave) cursor bases, bucket-contiguous stable layout
      int s = btot[tid];
#pragma unroll
      for (int ww = 0; ww < 16; ww++) { cur16[ww][tid] = s; s += cnt16[ww][tid]; }
    }
    __syncthreads();
    for (int i = tid; i < Nn; i += 1024) {
      int p = atomicAdd(&cur16[w][lens[i]], 1);
      order[p] = i;
    }
    return;
  }
  int i = blockIdx.x * 1024 + tid;
  if (i < 2 * Vv * Hh) {  // 65536: one thread per (d,c,u), all 4 banks (emb row reused)
    int u = i & 127, c = (i >> 7) & 255, d = i >> 15;
    const float* Wih = d ? Wih_b : Wih_f;
    const float* bih = d ? bih_b : bih_f;
    const float* bhh = d ? bhh_b : bhh_f;
    float acc[4];
#pragma unroll
    for (int bank = 0; bank < 4; bank++) {
      int j = bank * 128 + u;
      acc[bank] = bih[j] + bhh[j];
    }
    const float4* e4 = (const float4*)(emb + c * Ee);
#pragma unroll 4
    for (int k = 0; k < Ee / 4; k++) {
      float4 a = e4[k];
#pragma unroll
      for (int bank = 0; bank < 4; bank++) {
        float4 b = *(const float4*)(Wih + (bank * 128 + u) * Ee + 4 * k);
        acc[bank] = fmaf(a.x, b.x, acc[bank]); acc[bank] = fmaf(a.y, b.y, acc[bank]);
        acc[bank] = fmaf(a.z, b.z, acc[bank]); acc[bank] = fmaf(a.w, b.w, acc[bank]);
      }
    }
    float4 outv = make_float4(acc[0] * KS1, acc[1] * KS1, acc[2], acc[3] * KS1);
    ((float4*)XGq)[i] = outv;
  }
  if (i < 2 * 4 * 4 * 4 * 128 * 8) {  // 131072
    int e = i & 7, u = (i >> 3) & 127, g2 = (i >> 10) & 3,
        bank = (i >> 12) & 3, kt = (i >> 14) & 3, d = (i >> 16) & 1;
    int j = bank * 128 + u;
    int k = kt * 32 + g2 * 8 + e;
    const float* Whh = d ? Whh_b : Whh_f;
    float w = Whh[j * Hh + k];
    BP[i] = (_Float16)((bank == 2) ? w : w * KS1);
  }
}

// Pade(5,4) tanh: tanh x ~= x(x^4+105x^2+945)/(15x^4+420x^2+945); clamp num to +-den
// via v_med3_f32 (den>0, finite -> bit-identical to min/max pair, one op).
#define PADE_TANH(X, NUM, DEN)                                                \
    float X##_2 = (X) * (X);                                                  \
    float NUM = (X) * fmaf(X##_2, fmaf(X##_2, 1.0f, 105.0f), 945.0f);         \
    float DEN = fmaf(X##_2, fmaf(X##_2, 15.0f, 420.0f), 945.0f);              \
    NUM = __builtin_amdgcn_fmed3f(NUM, -DEN, DEN);

// Gates (round-6 math: measured-lowest busy-cycles — 3 exp2 + 2 Pade + 2 rcp per set):
// A=exp(-yi), B=exp(-yf), E=exp(-yo) via exp2 of prescaled accs; g,tanh(c) via Pade.
// cn = c/(1+B) + g/(1+A) = (c*aA*gd + gn*aB) * rcp(aA*aB*gd)
// hn = tanh(cn)/(1+E)    = tn * rcp(td*aE)
#define GATES(ACC, CS, HR, WLEN)                                              \
  _Pragma("unroll") for (int r = 0; r < 4; r++) {                             \
    float Av = __builtin_amdgcn_exp2f(ACC[0][r]);                             \
    float Bv = __builtin_amdgcn_exp2f(ACC[1][r]);                             \
    float yg = ACC[2][r];                                                     \
    float Ev = __builtin_amdgcn_exp2f(ACC[3][r]);                             \
    float aA = 1.0f + Av, aB = 1.0f + Bv, aE = 1.0f + Ev;                     \
    PADE_TANH(yg, gn, gd)                                                     \
    float R1 = __builtin_amdgcn_rcpf(aA * aB * gd);                           \
    float cn = fmaf(CS[r] * aA, gd, gn * aB) * R1;                            \
    PADE_TANH(cn, tn, td)                                                     \
    float R2 = __builtin_amdgcn_rcpf(td * aE);                                \
    float hn = tn * R2;                                                       \
    if (t < WLEN[r]) {                                                        \
      CS[r] = cn; HR[r] = hn;                                                 \
      hw[qg * 4 + r][u] = (_Float16)hn;                                       \
    }                                                                         \
  }

// float4 gather via time-major pre-shifted offsets: ONE ds_read_b128 of 4 char offsets
// (direction-reversal pre-applied at setup), then 4 coalesced dwordx4 loads.
#define LOADX(XV, TT) {                                                       \
    const int4 cc = *(const int4*)&idx_t[TT][qg * 4];                         \
    XV[0] = xq[cc.x + u]; XV[1] = xq[cc.y + u];                               \
    XV[2] = xq[cc.z + u]; XV[3] = xq[cc.w + u]; }

// ---- main (FROZEN at the r12 plateau — byte-identical): 2048 tasks (16 sorted words x
// dir), one 8-wave block each, longest first. Whh in VGPRs (Bf, 64). Per step:
// prefetched XGq gather -> acc; ds_read h A-frags (double-buffered LDS, ONE barrier/
// step); 16 MFMA; r6 gates; f16 h writeback.
__global__ __launch_bounds__(NTHR, 4) void bilstm_main(
    const int* __restrict__ cidx, const int* __restrict__ lens,
    const _Float16* __restrict__ BP, const float* __restrict__ XGq,
    const int* __restrict__ order, float* __restrict__ out) {
  __shared__ __align__(16) _Float16 hs[2][WB][136];  // dbuf; pad 136 -> 2-way bank (free)
  __shared__ __align__(16) int idx_t[Ll][WB];  // pre-shifted (c<<7), reversal pre-applied
  __shared__ int wid_s[WB];
  __shared__ int len_s[WB];

  const int tid = threadIdx.x;
  const int lane = tid & 63;
  const int wv = tid >> 6;        // wave 0..7
  const int qg = lane >> 4;       // quarter-group 0..3
  const int li = lane & 15;       // col within tile
  const int u = (wv << 4) + li;   // this lane's unit 0..127

  const int task = NTASK - 1 - (int)blockIdx.x;  // longest first
  const int g = task >> 1;
  const int d = task & 1;

  // Whh fragments -> registers FIRST (depend only on blockIdx): their L2 latency
  // hides under the order/idx/hs LDS setup below.
  half8 Bf[4][4];
  {
    const _Float16* BPd = BP + (size_t)d * 65536;
#pragma unroll
    for (int kt = 0; kt < 4; kt++)
#pragma unroll
      for (int bank = 0; bank < 4; bank++)
        Bf[kt][bank] = *(const half8*)(BPd + (size_t)((((kt * 4 + bank) * 4 + qg) * 128 + u) << 3));
  }

  if (tid < WB) { int w = order[g * WB + tid]; wid_s[tid] = w; len_s[tid] = lens[w]; }
  __syncthreads();
  for (int i = tid; i < WB * Ll; i += NTHR) {
    int w = i & 15, p = i >> 4;
    int pos = d ? (len_s[w] - 1 - p) : p;
    pos = pos < 0 ? 0 : pos;
    idx_t[p][w] = cidx[(size_t)wid_s[w] * Ll + pos] << 7;
  }
  for (int i = tid; i < (int)(2 * WB * 136 * sizeof(_Float16) / 16); i += NTHR)
    ((float4*)hs)[i] = make_float4(0.f, 0.f, 0.f, 0.f);
  __syncthreads();

  const int maxlen = len_s[WB - 1];  // ascending sort -> group max

  const f32x4* xq = (const f32x4*)(XGq + (size_t)d * (Vv * G4));

  int wlen0[4];
#pragma unroll
  for (int r = 0; r < 4; r++)
    wlen0[r] = len_s[qg * 4 + r];        // C/D row = (lane>>4)*4 + reg
  float cst0[4], hreg0[4];
#pragma unroll
  for (int r = 0; r < 4; r++) { cst0[r] = 0.0f; hreg0[r] = 0.0f; }

  f32x4 x4a[4];
  if (maxlen > 0) { LOADX(x4a, 0); }

  for (int t = 0; t < maxlen; t++) {
    _Float16 (*hw)[136] = hs[t & 1];                 // write buffer
    const _Float16 (*hr)[136] = hs[(t ^ 1) & 1];     // read buffer = (t-1)&1

    // acc init from prefetched gather (loads issued last iteration)
    f32x4 acc0[4];
#pragma unroll
    for (int bank = 0; bank < 4; bank++)
#pragma unroll
      for (int r = 0; r < 4; r++) acc0[bank][r] = x4a[r][bank];

    if (t > 0) {  // h==0 at t=0: matmul contributes nothing
#pragma unroll
      for (int kt = 0; kt < 4; kt++) {
        half8 a0 = *(const half8*)&hr[li][kt * 32 + qg * 8];
#pragma unroll
        for (int bank = 0; bank < 4; bank++)
          acc0[bank] = __builtin_amdgcn_mfma_f32_16x16x32_f16(a0, Bf[kt][bank], acc0[bank], 0, 0, 0);
      }
    }

    // prefetch next step's gather; latency hides under gates + co-resident block.
    if (t + 1 < maxlen) { LOADX(x4a, t + 1); }

    GATES(acc0, cst0, hreg0, wlen0);

    __syncthreads();  // writes to hs[t&1] visible before next step reads it
  }

  // output from fp32 regs
#pragma unroll
  for (int r = 0; r < 4; r++)
    out[(size_t)wid_s[qg * 4 + r] * (2 * Hh) + d * Hh + u] = hreg0[r];
}

extern "C" void kernel_launch(void* const* d_in, const int* in_sizes, int n_in,
                              void* d_out, int out_size, void* d_ws, size_t ws_size,
                              hipStream_t stream) {
  const int* cidx = (const int*)d_in[0];
  const int* lens = (const int*)d_in[1];
  const float* emb = (const float*)d_in[2];
  const float* Wih_f = (const float*)d_in[3];
  const float* Whh_f = (const float*)d_in[4];
  const float* bih_f = (const float*)d_in[5];
  const float* bhh_f = (const float*)d_in[6];
  const float* Wih_b = (const float*)d_in[7];
  const float* Whh_b = (const float*)d_in[8];
  const float* bih_b = (const float*)d_in[9];
  const float* bhh_b = (const float*)d_in[10];
  float* out = (float*)d_out;

  // ws: BP f16 [131072] = 256KB | XGq f32 [2*256*512] = 1MB | order[N]
  char* base = (char*)d_ws;
  _Float16* BP = (_Float16*)base;
  float* XGq = (float*)(base + 262144);
  int* order = (int*)(base + 262144 + 1048576);

  prep_sort_kernel<<<129, 1024, 0, stream>>>(
      emb, Wih_f, Whh_f, bih_f, bhh_f, Wih_b, Whh_b, bih_b, bhh_b, lens, BP, XGq, order);
  bilstm_main<<<NTASK, NTHR, 0, stream>>>(cidx, lens, BP, XGq, order, out);
}

// Round 14
// 120.454 us; speedup vs baseline: 1.0408x; 1.0408x over previous
//
#include <hip/hip_runtime.h>
#include <math.h>

#define Vv 256
#define Ee 64
#define Hh 128
#define Nn 16384
#define Ll 24
#define G4 512      // 4*H
#define WB 16       // words per task (single M-tile; 2 blocks/CU)
#define NTHR 512    // 8 waves
#define NGRP (Nn / WB)      // 1024 groups
#define NTASK (NGRP * 2)    // 2048 tasks (group x dir) = grid

typedef _Float16 half8 __attribute__((ext_vector_type(8)));
typedef float f32x4 __attribute__((ext_vector_type(4)));

#define KS1 (-1.4426950408889634f)   // -log2(e): i,f,o rows -> 2^s = exp(-y)

// ---- fused prep + sort (blocks 0..511: prep; block 512: counting sort in LDS)
// XGq[d][c][u][bank] (f32, float4 per (c,u)): (emb[c]@Wih_d[j] + bih[j]+bhh[j]) * scale(bank),
//   j = bank*128+u. scale = KS1 for i,f,o (exp2-ready); g bank (2) RAW for Pade tanh.
//   r8 lesson: keep float4-per-(c,u); scalar gathers on bank-major blew HBM 5.6MB->908MB.
// BP[d][kt][bank][g2][u][e] (f16): Whh_d[j][k]*scale(bank), k=kt*32+g2*8+e (B-frag order).
__global__ void prep_sort_kernel(const float* __restrict__ emb,
                                 const float* __restrict__ Wih_f, const float* __restrict__ Whh_f,
                                 const float* __restrict__ bih_f, const float* __restrict__ bhh_f,
                                 const float* __restrict__ Wih_b, const float* __restrict__ Whh_b,
                                 const float* __restrict__ bih_b, const float* __restrict__ bhh_b,
                                 const int* __restrict__ lens,
                                 _Float16* __restrict__ BP, float* __restrict__ XGq,
                                 int* __restrict__ order) {
  const int tid = threadIdx.x;
  if (blockIdx.x == 512) {
    // ---- sort block: per-wave-private histograms/cursors (4x less LDS-atomic
    // contention than one shared copy; bucket-contiguous order preserved).
    __shared__ int cnt4[4][32];
    __shared__ int cur4[4][32];
    const int w = tid >> 6;
    if (tid < 128) ((int*)cnt4)[tid] = 0;
    __syncthreads();
    for (int i = tid; i < Nn; i += 256) atomicAdd(&cnt4[w][lens[i]], 1);
    __syncthreads();
    if (tid == 0) {
      int s = 0;
      for (int b = 0; b <= Ll; b++)
        for (int ww = 0; ww < 4; ww++) { cur4[ww][b] = s; s += cnt4[ww][b]; }
    }
    __syncthreads();
    for (int i = tid; i < Nn; i += 256) {
      int p = atomicAdd(&cur4[w][lens[i]], 1);
      order[p] = i;
    }
    return;
  }
  int i = blockIdx.x * 256 + tid;
  if (i < 2 * Vv * Hh) {  // 65536 threads: one per (d,c,u), all 4 banks (emb row reused)
    int u = i & 127, c = (i >> 7) & 255, d = i >> 15;
    const float* Wih = d ? Wih_b : Wih_f;
    const float* bih = d ? bih_b : bih_f;
    const float* bhh = d ? bhh_b : bhh_f;
    float acc[4];
#pragma unroll
    for (int bank = 0; bank < 4; bank++) {
      int j = bank * 128 + u;
      acc[bank] = bih[j] + bhh[j];
    }
    const float4* e4 = (const float4*)(emb + c * Ee);
#pragma unroll 4
    for (int k = 0; k < Ee / 4; k++) {
      float4 a = e4[k];
#pragma unroll
      for (int bank = 0; bank < 4; bank++) {
        float4 b = *(const float4*)(Wih + (bank * 128 + u) * Ee + 4 * k);
        acc[bank] = fmaf(a.x, b.x, acc[bank]); acc[bank] = fmaf(a.y, b.y, acc[bank]);
        acc[bank] = fmaf(a.z, b.z, acc[bank]); acc[bank] = fmaf(a.w, b.w, acc[bank]);
      }
    }
    float4 outv = make_float4(acc[0] * KS1, acc[1] * KS1, acc[2], acc[3] * KS1);
    ((float4*)XGq)[i] = outv;
  }
  if (i < 2 * 4 * 4 * 4 * 128 * 8) {  // 131072
    int e = i & 7, u = (i >> 3) & 127, g2 = (i >> 10) & 3,
        bank = (i >> 12) & 3, kt = (i >> 14) & 3, d = (i >> 16) & 1;
    int j = bank * 128 + u;
    int k = kt * 32 + g2 * 8 + e;
    const float* Whh = d ? Whh_b : Whh_f;
    float w = Whh[j * Hh + k];
    BP[i] = (_Float16)((bank == 2) ? w : w * KS1);
  }
}

// Pade(5,4) tanh: tanh x ~= x(x^4+105x^2+945)/(15x^4+420x^2+945); clamp num to +-den
// via v_med3_f32 (den>0, finite -> bit-identical to min/max pair, one op).
#define PADE_TANH(X, NUM, DEN)                                                \
    float X##_2 = (X) * (X);                                                  \
    float NUM = (X) * fmaf(X##_2, fmaf(X##_2, 1.0f, 105.0f), 945.0f);         \
    float DEN = fmaf(X##_2, fmaf(X##_2, 15.0f, 420.0f), 945.0f);              \
    NUM = __builtin_amdgcn_fmed3f(NUM, -DEN, DEN);

// Gates (round-6 math: measured-lowest busy-cycles — 3 exp2 + 2 Pade + 2 rcp per set):
// A=exp(-yi), B=exp(-yf), E=exp(-yo) via exp2 of prescaled accs; g,tanh(c) via Pade.
// cn = c/(1+B) + g/(1+A) = (c*aA*gd + gn*aB) * rcp(aA*aB*gd)
// hn = tanh(cn)/(1+E)    = tn * rcp(td*aE)
#define GATES(ACC, CS, HR, WLEN)                                              \
  _Pragma("unroll") for (int r = 0; r < 4; r++) {                             \
    float Av = __builtin_amdgcn_exp2f(ACC[0][r]);                             \
    float Bv = __builtin_amdgcn_exp2f(ACC[1][r]);                             \
    float yg = ACC[2][r];                                                     \
    float Ev = __builtin_amdgcn_exp2f(ACC[3][r]);                             \
    float aA = 1.0f + Av, aB = 1.0f + Bv, aE = 1.0f + Ev;                     \
    PADE_TANH(yg, gn, gd)                                                     \
    float R1 = __builtin_amdgcn_rcpf(aA * aB * gd);                           \
    float cn = fmaf(CS[r] * aA, gd, gn * aB) * R1;                            \
    PADE_TANH(cn, tn, td)                                                     \
    float R2 = __builtin_amdgcn_rcpf(td * aE);                                \
    float hn = tn * R2;                                                       \
    if (t < WLEN[r]) {                                                        \
      CS[r] = cn; HR[r] = hn;                                                 \
      hw[qg * 4 + r][u] = (_Float16)hn;                                       \
    }                                                                         \
  }

// float4 gather via time-major pre-shifted offsets: ONE ds_read_b128 of 4 char offsets
// (direction-reversal pre-applied at setup), then 4 coalesced dwordx4 loads.
#define LOADX(XV, TT) {                                                       \
    const int4 cc = *(const int4*)&idx_t[TT][qg * 4];                         \
    XV[0] = xq[cc.x + u]; XV[1] = xq[cc.y + u];                               \
    XV[2] = xq[cc.z + u]; XV[3] = xq[cc.w + u]; }

// ---- main: 2048 tasks (16 sorted words x dir), one 8-wave block each, longest first.
// r7 structure (single M-tile, 2 blocks/CU) + r6 gate math + float4 gather/prefetch.
// Whh in VGPRs (Bf, 64). Per step: prefetched XGq gather -> acc; ds_read h A-frags
// (double-buffered LDS, ONE barrier/step); 16 MFMA; r6 gates; f16 h writeback.
__global__ __launch_bounds__(NTHR, 4) void bilstm_main(
    const int* __restrict__ cidx, const int* __restrict__ lens,
    const _Float16* __restrict__ BP, const float* __restrict__ XGq,
    const int* __restrict__ order, float* __restrict__ out) {
  __shared__ __align__(16) _Float16 hs[2][WB][136];  // dbuf; pad 136 -> 2-way bank (free)
  __shared__ __align__(16) int idx_t[Ll][WB];  // pre-shifted (c<<7), reversal pre-applied
  __shared__ int wid_s[WB];
  __shared__ int len_s[WB];

  const int tid = threadIdx.x;
  const int lane = tid & 63;
  const int wv = tid >> 6;        // wave 0..7
  const int qg = lane >> 4;       // quarter-group 0..3
  const int li = lane & 15;       // col within tile
  const int u = (wv << 4) + li;   // this lane's unit 0..127

  const int task = NTASK - 1 - (int)blockIdx.x;  // longest first
  const int g = task >> 1;
  const int d = task & 1;

  // Whh fragments -> registers FIRST (depend only on blockIdx): their L2 latency
  // hides under the order/idx/hs LDS setup below.
  half8 Bf[4][4];
  {
    const _Float16* BPd = BP + (size_t)d * 65536;
#pragma unroll
    for (int kt = 0; kt < 4; kt++)
#pragma unroll
      for (int bank = 0; bank < 4; bank++)
        Bf[kt][bank] = *(const half8*)(BPd + (size_t)((((kt * 4 + bank) * 4 + qg) * 128 + u) << 3));
  }

  if (tid < WB) { int w = order[g * WB + tid]; wid_s[tid] = w; len_s[tid] = lens[w]; }
  __syncthreads();
  for (int i = tid; i < WB * Ll; i += NTHR) {
    int w = i & 15, p = i >> 4;
    int pos = d ? (len_s[w] - 1 - p) : p;
    pos = pos < 0 ? 0 : pos;
    idx_t[p][w] = cidx[(size_t)wid_s[w] * Ll + pos] << 7;
  }
  for (int i = tid; i < (int)(2 * WB * 136 * sizeof(_Float16) / 16); i += NTHR)
    ((float4*)hs)[i] = make_float4(0.f, 0.f, 0.f, 0.f);
  __syncthreads();

  const int maxlen = len_s[WB - 1];  // ascending sort -> group max

  const f32x4* xq = (const f32x4*)(XGq + (size_t)d * (Vv * G4));

  int wlen0[4];
#pragma unroll
  for (int r = 0; r < 4; r++)
    wlen0[r] = len_s[qg * 4 + r];        // C/D row = (lane>>4)*4 + reg
  float cst0[4], hreg0[4];
#pragma unroll
  for (int r = 0; r < 4; r++) { cst0[r] = 0.0f; hreg0[r] = 0.0f; }

  f32x4 x4a[4];
  if (maxlen > 0) { LOADX(x4a, 0); }

  for (int t = 0; t < maxlen; t++) {
    _Float16 (*hw)[136] = hs[t & 1];                 // write buffer
    const _Float16 (*hr)[136] = hs[(t ^ 1) & 1];     // read buffer = (t-1)&1

    // acc init from prefetched gather (loads issued last iteration)
    f32x4 acc0[4];
#pragma unroll
    for (int bank = 0; bank < 4; bank++)
#pragma unroll
      for (int r = 0; r < 4; r++) acc0[bank][r] = x4a[r][bank];

    if (t > 0) {  // h==0 at t=0: matmul contributes nothing
#pragma unroll
      for (int kt = 0; kt < 4; kt++) {
        half8 a0 = *(const half8*)&hr[li][kt * 32 + qg * 8];
#pragma unroll
        for (int bank = 0; bank < 4; bank++)
          acc0[bank] = __builtin_amdgcn_mfma_f32_16x16x32_f16(a0, Bf[kt][bank], acc0[bank], 0, 0, 0);
      }
    }

    // prefetch next step's gather; latency hides under gates + co-resident block.
    if (t + 1 < maxlen) { LOADX(x4a, t + 1); }

    GATES(acc0, cst0, hreg0, wlen0);

    __syncthreads();  // writes to hs[t&1] visible before next step reads it
  }

  // output from fp32 regs
#pragma unroll
  for (int r = 0; r < 4; r++)
    out[(size_t)wid_s[qg * 4 + r] * (2 * Hh) + d * Hh + u] = hreg0[r];
}

extern "C" void kernel_launch(void* const* d_in, const int* in_sizes, int n_in,
                              void* d_out, int out_size, void* d_ws, size_t ws_size,
                              hipStream_t stream) {
  const int* cidx = (const int*)d_in[0];
  const int* lens = (const int*)d_in[1];
  const float* emb = (const float*)d_in[2];
  const float* Wih_f = (const float*)d_in[3];
  const float* Whh_f = (const float*)d_in[4];
  const float* bih_f = (const float*)d_in[5];
  const float* bhh_f = (const float*)d_in[6];
  const float* Wih_b = (const float*)d_in[7];
  const float* Whh_b = (const float*)d_in[8];
  const float* bih_b = (const float*)d_in[9];
  const float* bhh_b = (const float*)d_in[10];
  float* out = (float*)d_out;

  // ws: BP f16 [131072] = 256KB | XGq f32 [2*256*512] = 1MB | order[N]
  char* base = (char*)d_ws;
  _Float16* BP = (_Float16*)base;
  float* XGq = (float*)(base + 262144);
  int* order = (int*)(base + 262144 + 1048576);

  prep_sort_kernel<<<513, 256, 0, stream>>>(
      emb, Wih_f, Whh_f, bih_f, bhh_f, Wih_b, Whh_b, bih_b, bhh_b, lens, BP, XGq, order);
  bilstm_main<<<NTASK, NTHR, 0, stream>>>(cidx, lens, BP, XGq, order, out);
}